// Round 8
// baseline (303.425 us; speedup 1.0000x reference)
//
#include <hip/hip_runtime.h>
#include <hip/hip_bf16.h>

#define N_NODES 50000
#define N_RELS 8
#define IN_DIM 128
#define OUT_DIM 128
#define N_EDGES 800000
#define NR (N_NODES * N_RELS)              /* 400000 keys (tgt*8+rel) */
#define KDIM (N_RELS * IN_DIM)             /* 1024 = GEMM K */
#define SCAN_ELEMS 2048
#define SCAN_NBLK ((NR + SCAN_ELEMS - 1) / SCAN_ELEMS)  /* 196 */
#define M_PAD 50048                        /* 782 blocks * 64 rows */
#define CNT_BLKS ((N_EDGES / 4 + 255) / 256)   /* 782 */
#define CW_BLKS ((N_RELS * IN_DIM * OUT_DIM + 255) / 256) /* 512 */
#define FB_BLKS ((N_NODES * IN_DIM / 8 + 255) / 256)      /* 3125 */

typedef __attribute__((ext_vector_type(8))) short bf16x8;
typedef __attribute__((ext_vector_type(4))) float floatx4;

__device__ inline unsigned short f2bf(float f) {
    unsigned u = __builtin_bit_cast(unsigned, f);
    u += 0x7fff + ((u >> 16) & 1);   // round-to-nearest-even
    return (unsigned short)(u >> 16);
}
__device__ inline float bflo(unsigned u) {   // low bf16 of a packed pair
    return __builtin_bit_cast(float, u << 16);
}
__device__ inline float bfhi(unsigned u) {   // high bf16 of a packed pair
    return __builtin_bit_cast(float, u & 0xffff0000u);
}

// ---------------- prep: histogram + W-conversion + feature-conversion ----------------
// blocks [0, CNT_BLKS): histogram of keys (4 edges/thread via int4 x3;
//   atomics are fire-and-forget -> no dependent latency chain)
// blocks [CNT_BLKS, +CW_BLKS): W[r][i][o] fp32 -> fragment-major bf16 Wtf:
//   Wtf[((nt*32+ks)*64+lane)*8+e] = W for B-frag (n=nt*16+(lane&15), k=ks*32+(lane>>4)*8+e)
//   so each B-fragment load in the GEMM is one contiguous 1 KB wave read.
// blocks [CNT_BLKS+CW_BLKS, +FB_BLKS): features fp32 -> bf16 featB (row = 256 B)
__global__ void prep_kernel(const int* __restrict__ tri, const float* __restrict__ W,
                            const float* __restrict__ features,
                            int* __restrict__ cnt, unsigned short* __restrict__ Wtf,
                            unsigned short* __restrict__ featB) {
    const int b = blockIdx.x;
    if (b < CNT_BLKS) {
        int t = b * 256 + threadIdx.x;
        if (t >= N_EDGES / 4) return;
        const int4* tri4 = (const int4*)tri;
        int4 a = tri4[3 * t], v = tri4[3 * t + 1], c = tri4[3 * t + 2];
        // edges: (a.x,a.y,a.z) (a.w,v.x,v.y) (v.z,v.w,c.x) (c.y,c.z,c.w)
        atomicAdd(&cnt[a.z * N_RELS + a.y], 1);
        atomicAdd(&cnt[v.y * N_RELS + v.x], 1);
        atomicAdd(&cnt[c.x * N_RELS + v.w], 1);
        atomicAdd(&cnt[c.w * N_RELS + c.z], 1);
    } else if (b < CNT_BLKS + CW_BLKS) {
        int idx = (b - CNT_BLKS) * 256 + threadIdx.x;   // 0 .. 131071
        if (idx >= N_RELS * IN_DIM * OUT_DIM) return;
        int e  = idx & 7;
        int l  = (idx >> 3) & 63;
        int ks = (idx >> 9) & 31;
        int nt = idx >> 14;
        int o = nt * 16 + (l & 15);
        int k = ks * 32 + (l >> 4) * 8 + e;             // global K index
        Wtf[idx] = f2bf(W[(k >> 7) * (IN_DIM * OUT_DIM) + (k & 127) * OUT_DIM + o]);
    } else {
        int t = (b - CNT_BLKS - CW_BLKS) * 256 + threadIdx.x;   // 8 floats each
        if (t >= N_NODES * IN_DIM / 8) return;
        const float4* f4 = (const float4*)features;
        float4 x = f4[2 * t], y = f4[2 * t + 1];
        uint4 o;
        o.x = (unsigned)f2bf(x.x) | ((unsigned)f2bf(x.y) << 16);
        o.y = (unsigned)f2bf(x.z) | ((unsigned)f2bf(x.w) << 16);
        o.z = (unsigned)f2bf(y.x) | ((unsigned)f2bf(y.y) << 16);
        o.w = (unsigned)f2bf(y.z) | ((unsigned)f2bf(y.w) << 16);
        ((uint4*)featB)[t] = o;
    }
}

// ---------------- single-pass scan (decoupled lookback) ----------------
// Re-landed as an isolated A/B vs round 5 (round 6 proved the agg shfl fix +
// 3-pass scan passes; audit says this lookback is correct — if this round
// fails, the scan is convicted and reverts permanently).
// 196 blocks << device capacity -> all co-resident, spin cannot deadlock.
// flags[b]: (value<<2) | state; state 1 = aggregate ready, 2 = inclusive ready.
// flags zeroed by the cnt memset (contiguous region). Values <= 800000 so
// value<<2 fits easily in 32 bits.
__global__ __launch_bounds__(256) void scan_kernel(
    const int* __restrict__ cnt, unsigned* __restrict__ flags,
    int* __restrict__ segOff, int* __restrict__ cursor)
{
    __shared__ int s[256];
    __shared__ int sbase;
    const int b = blockIdx.x, t = threadIdx.x;
    const int base = b * SCAN_ELEMS + t * 8;
    int v[8]; int sum = 0;
#pragma unroll
    for (int k = 0; k < 8; ++k) {
        int i = base + k;
        v[k] = (i < NR) ? cnt[i] : 0;
        sum += v[k];
    }
    s[t] = sum; __syncthreads();
    for (int off = 1; off < 256; off <<= 1) {          // inclusive block scan
        int x = (t >= off) ? s[t - off] : 0;
        __syncthreads();
        s[t] += x;
        __syncthreads();
    }
    if (t == 0) {
        const int blockAgg = s[255];
        if (b == 0) {
            __hip_atomic_store(&flags[0], ((unsigned)blockAgg << 2) | 2u,
                               __ATOMIC_RELEASE, __HIP_MEMORY_SCOPE_AGENT);
            sbase = 0;
        } else {
            __hip_atomic_store(&flags[b], ((unsigned)blockAgg << 2) | 1u,
                               __ATOMIC_RELEASE, __HIP_MEMORY_SCOPE_AGENT);
            int acc = 0, p = b - 1;
            while (true) {
                unsigned f = __hip_atomic_load(&flags[p], __ATOMIC_ACQUIRE,
                                               __HIP_MEMORY_SCOPE_AGENT);
                unsigned st = f & 3u;
                if (st == 0u) continue;
                acc += (int)(f >> 2);
                if (st == 2u) break;
                --p;
            }
            __hip_atomic_store(&flags[b], (((unsigned)(acc + blockAgg)) << 2) | 2u,
                               __ATOMIC_RELEASE, __HIP_MEMORY_SCOPE_AGENT);
            sbase = acc;
        }
    }
    __syncthreads();
    int run = sbase + s[t] - sum;   // exclusive offset for this thread's chunk
#pragma unroll
    for (int k = 0; k < 8; ++k) {
        int i = base + k;
        if (i < NR) { segOff[i] = run; cursor[i] = run; run += v[k]; }
    }
    if (b == 0 && t == 0) segOff[NR] = N_EDGES;
}

// ---------------- scatter: 1 edge per thread (round 7 win) ----------------
__global__ void scatter_kernel(const int* __restrict__ tri, int* __restrict__ cursor,
                               int* __restrict__ sortedSrc) {
    int e = blockIdx.x * 256 + threadIdx.x;
    if (e >= N_EDGES) return;
    int src = tri[3 * e];
    int rel = tri[3 * e + 1];
    int tgt = tri[3 * e + 2];
    int p = atomicAdd(&cursor[tgt * N_RELS + rel], 1);
    sortedSrc[p] = src;
}

// ---------------- phase A: per-node segment mean -> bf16 agg row ----------------
// One wave per node; QUARTER-wave per edge: quarter q (16 lanes x 16 B) covers
// one full 256 B bf16 row, so 4 edges are in flight per wave (was 2). Pass p
// gives quarter q rel r = 4p+q. Trip count is wave-uniform jmax = max over the
// 4 quarters (two full-exec shfl_xor reductions), so every __shfl executes at
// FULL exec (round-5 lesson: inactive-lane shfl reads are undefined); only the
// accumulate body is predicated by j < len. Loads/stores are dwordx4.
__global__ __launch_bounds__(256) void agg_kernel(
    const int* __restrict__ sortedSrc, const int* __restrict__ segOff,
    const unsigned short* __restrict__ featB, unsigned short* __restrict__ aggG)
{
    const int wave = threadIdx.x >> 6, lane = threadIdx.x & 63;
    const int node = blockIdx.x * 4 + wave;
    const int q = lane >> 4, l16 = lane & 15;

    int bnd = 0;
    if (lane < 9) bnd = segOff[node * N_RELS + lane];
    int s[9];
#pragma unroll
    for (int i = 0; i < 9; ++i) s[i] = __shfl(bnd, i);

    const int e0 = s[0], eN = s[8];
    int srcw = 0;
    if (e0 + lane < eN) srcw = sortedSrc[e0 + lane];   // window of 64 srcs

    const unsigned short* fb = featB + 8 * l16;        // dims 8*l16 .. 8*l16+7
    unsigned short* dst = aggG + (size_t)node * KDIM + 8 * l16;

#pragma unroll
    for (int p = 0; p < 2; ++p) {
        const int r = 4 * p + q;
        const int s0v = s[r], s1v = s[r + 1];
        const int len = s1v - s0v;
        int m0x = __shfl_xor(len, 16);                 // full exec
        int jm = (len > m0x) ? len : m0x;
        int m1x = __shfl_xor(jm, 32);                  // full exec
        const int jmax = (jm > m1x) ? jm : m1x;        // wave-uniform
        float a0 = 0.f, a1 = 0.f, a2 = 0.f, a3 = 0.f;
        float a4 = 0.f, a5 = 0.f, a6 = 0.f, a7 = 0.f;
        for (int j = 0; j < jmax; ++j) {               // uniform trip count
            const int e = s0v + j;
            const int i0 = e - e0;
            const int swin = __shfl(srcw, i0 & 63);    // full exec, safe
            if (j < len) {
                const int src = (i0 < 64) ? swin : sortedSrc[e];
                uint4 u = *(const uint4*)&fb[src * IN_DIM];
                a0 += bflo(u.x); a1 += bfhi(u.x);
                a2 += bflo(u.y); a3 += bfhi(u.y);
                a4 += bflo(u.z); a5 += bfhi(u.z);
                a6 += bflo(u.w); a7 += bfhi(u.w);
            }
        }
        const float inv = (len > 0) ? 1.0f / (float)len : 0.0f;
        uint4 pk;
        pk.x = (unsigned)f2bf(a0 * inv) | ((unsigned)f2bf(a1 * inv) << 16);
        pk.y = (unsigned)f2bf(a2 * inv) | ((unsigned)f2bf(a3 * inv) << 16);
        pk.z = (unsigned)f2bf(a4 * inv) | ((unsigned)f2bf(a5 * inv) << 16);
        pk.w = (unsigned)f2bf(a6 * inv) | ((unsigned)f2bf(a7 * inv) << 16);
        *(uint4*)&dst[r * IN_DIM] = pk;                // each quarter stores its rel row
    }
}

// ---------------- phase B: out[M_PAD x 128] = agg @ W + bias ----------------
// Block = 64 rows x 128 cols, 4 waves, wave-tile 32x64. A staged to LDS via
// global_load_lds (16 B) with XOR-16 swizzle: LDS[row][u] = global[row][u^(row&15)]
//  - staging reads: 16 contiguous lanes cover one full 256 B row segment
//  - A-frag ds_read_b128: 16 lanes hit perm(0..15) 16B units -> 2-way = free
// B-frags are contiguous 1 KB loads from fragment-major Wtf (L2-resident).
__global__ __launch_bounds__(256) void gemm_kernel(
    const unsigned short* __restrict__ aggG,
    const unsigned short* __restrict__ Wtf,
    const float* __restrict__ bias,
    float* __restrict__ out)
{
    __shared__ unsigned short Abuf[64 * 128];   // 16 KB, row stride 256 B
    const int tid = threadIdx.x;
    const int wave = tid >> 6, lane = tid & 63;
    const int qk = lane >> 4, ln16 = lane & 15;
    const int m0 = blockIdx.x * 64;
    const int wm = wave & 1, wn = wave >> 1;

    floatx4 acc[2][4];
#pragma unroll
    for (int st = 0; st < 2; ++st)
#pragma unroll
        for (int nt = 0; nt < 4; ++nt) acc[st][nt] = (floatx4){0.f, 0.f, 0.f, 0.f};

    const int l4 = lane >> 4, l15 = lane & 15;

    for (int c = 0; c < 8; ++c) {
        __syncthreads();                 // previous chunk fully consumed
#pragma unroll
        for (int i = 0; i < 4; ++i) {
            const int row = wave * 16 + i * 4 + l4;          // 0..63
            const int unit = l15 ^ (row & 15);
            const unsigned short* g =
                aggG + (size_t)(m0 + row) * KDIM + c * 128 + unit * 8;
            __builtin_amdgcn_global_load_lds(
                (const __attribute__((address_space(1))) unsigned int*)g,
                (__attribute__((address_space(3))) unsigned int*)&Abuf[(wave * 16 + i * 4) * 128],
                16, 0, 0);
        }
        __syncthreads();                 // staging visible (vmcnt drained)

#pragma unroll
        for (int ksl = 0; ksl < 4; ++ksl) {
            const int ks = c * 4 + ksl;
            bf16x8 a[2];
#pragma unroll
            for (int st = 0; st < 2; ++st) {
                const int r = wm * 32 + st * 16 + ln16;
                const int u = (ksl * 4 + qk) ^ (r & 15);
                a[st] = *(const bf16x8*)&Abuf[r * 128 + u * 8];
            }
#pragma unroll
            for (int nt = 0; nt < 4; ++nt) {
                const int ntg = wn * 4 + nt;
                bf16x8 b = *(const bf16x8*)&Wtf[(size_t)((ntg * 32 + ks) * 64 + lane) * 8];
                acc[0][nt] = __builtin_amdgcn_mfma_f32_16x16x32_bf16(a[0], b, acc[0][nt], 0, 0, 0);
                acc[1][nt] = __builtin_amdgcn_mfma_f32_16x16x32_bf16(a[1], b, acc[1][nt], 0, 0, 0);
            }
        }
    }

    // D layout: col = lane&15, row = (lane>>4)*4 + reg
#pragma unroll
    for (int nt = 0; nt < 4; ++nt) {
        const int o = (wn * 4 + nt) * 16 + ln16;
        const float bv = bias[o];
#pragma unroll
        for (int st = 0; st < 2; ++st)
#pragma unroll
            for (int j = 0; j < 4; ++j) {
                const int t = m0 + wm * 32 + st * 16 + qk * 4 + j;
                if (t < N_NODES) out[(size_t)t * OUT_DIM + o] = acc[st][nt][j] + bv;
            }
    }
}

extern "C" void kernel_launch(void* const* d_in, const int* in_sizes, int n_in,
                              void* d_out, int out_size, void* d_ws, size_t ws_size,
                              hipStream_t stream)
{
    const int*   tri      = (const int*)d_in[0];
    const float* features = (const float*)d_in[1];
    const float* W        = (const float*)d_in[2];
    const float* bias     = (const float*)d_in[3];
    float* out = (float*)d_out;

    char* ws = (char*)d_ws;
    unsigned short* Wtf = (unsigned short*)ws; ws += (size_t)OUT_DIM * KDIM * 2;  // 256 KB
    int* cnt        = (int*)ws;      ws += (size_t)NR * 4;
    unsigned* flags = (unsigned*)ws; ws += 256 * 4;          // contiguous with cnt (one memset)
    int* segOff     = (int*)ws;      ws += (size_t)(NR + 4) * 4;
    int* cursor     = (int*)ws;      ws += (size_t)NR * 4;
    int* sortedSrc  = (int*)ws;      ws += (size_t)N_EDGES * 4;
    unsigned short* featB = (unsigned short*)ws; ws += (size_t)N_NODES * IN_DIM * 2;  // 12.8 MB
    unsigned short* aggG  = (unsigned short*)ws; ws += (size_t)M_PAD * KDIM * 2;      // 102.5 MB
    (void)ws_size; (void)in_sizes; (void)n_in; (void)out_size;

    hipMemsetAsync(cnt, 0, (NR + 256) * sizeof(int), stream);   // cnt + flags
    prep_kernel<<<CNT_BLKS + CW_BLKS + FB_BLKS, 256, 0, stream>>>(tri, W, features, cnt, Wtf, featB);
    scan_kernel<<<SCAN_NBLK, 256, 0, stream>>>(cnt, flags, segOff, cursor);
    scatter_kernel<<<(N_EDGES + 255) / 256, 256, 0, stream>>>(tri, cursor, sortedSrc);
    agg_kernel<<<N_NODES / 4, 256, 0, stream>>>(sortedSrc, segOff, featB, aggG);
    gemm_kernel<<<M_PAD / 64, 256, 0, stream>>>(aggG, Wtf, bias, out);
}

// Round 9
// 262.757 us; speedup vs baseline: 1.1548x; 1.1548x over previous
//
#include <hip/hip_runtime.h>
#include <hip/hip_bf16.h>

#define N_NODES 50000
#define N_RELS 8
#define IN_DIM 128
#define OUT_DIM 128
#define N_EDGES 800000
#define NR (N_NODES * N_RELS)              /* 400000 keys (tgt*8+rel) */
#define KDIM (N_RELS * IN_DIM)             /* 1024 = GEMM K */
#define SCAN_ELEMS 2048
#define SCAN_NBLK ((NR + SCAN_ELEMS - 1) / SCAN_ELEMS)  /* 196 */
#define M_PAD 50048                        /* 782 blocks * 64 rows */
#define CNT_BLKS ((N_EDGES / 4 + 255) / 256)   /* 782 */
#define CW_BLKS ((N_RELS * IN_DIM * OUT_DIM + 255) / 256) /* 512 */
#define FB_BLKS ((N_NODES * IN_DIM / 8 + 255) / 256)      /* 3125 */

typedef __attribute__((ext_vector_type(8))) short bf16x8;
typedef __attribute__((ext_vector_type(4))) float floatx4;

__device__ inline unsigned short f2bf(float f) {
    unsigned u = __builtin_bit_cast(unsigned, f);
    u += 0x7fff + ((u >> 16) & 1);   // round-to-nearest-even
    return (unsigned short)(u >> 16);
}
__device__ inline float bflo(unsigned u) {   // low bf16 of a packed pair
    return __builtin_bit_cast(float, u << 16);
}
__device__ inline float bfhi(unsigned u) {   // high bf16 of a packed pair
    return __builtin_bit_cast(float, u & 0xffff0000u);
}

// ---------------- prep: histogram + W-conversion + feature-conversion ----------------
// blocks [0, CNT_BLKS): histogram of keys (4 edges/thread via int4 x3;
//   atomics are fire-and-forget -> no dependent latency chain)
// blocks [CNT_BLKS, +CW_BLKS): W[r][i][o] fp32 -> fragment-major bf16 Wtf:
//   Wtf[((nt*32+ks)*64+lane)*8+e] = W for B-frag (n=nt*16+(lane&15), k=ks*32+(lane>>4)*8+e)
//   so each B-fragment load in the GEMM is one contiguous 1 KB wave read.
// blocks [CNT_BLKS+CW_BLKS, +FB_BLKS): features fp32 -> bf16 featB (row = 256 B)
__global__ void prep_kernel(const int* __restrict__ tri, const float* __restrict__ W,
                            const float* __restrict__ features,
                            int* __restrict__ cnt, unsigned short* __restrict__ Wtf,
                            unsigned short* __restrict__ featB) {
    const int b = blockIdx.x;
    if (b < CNT_BLKS) {
        int t = b * 256 + threadIdx.x;
        if (t >= N_EDGES / 4) return;
        const int4* tri4 = (const int4*)tri;
        int4 a = tri4[3 * t], v = tri4[3 * t + 1], c = tri4[3 * t + 2];
        // edges: (a.x,a.y,a.z) (a.w,v.x,v.y) (v.z,v.w,c.x) (c.y,c.z,c.w)
        atomicAdd(&cnt[a.z * N_RELS + a.y], 1);
        atomicAdd(&cnt[v.y * N_RELS + v.x], 1);
        atomicAdd(&cnt[c.x * N_RELS + v.w], 1);
        atomicAdd(&cnt[c.w * N_RELS + c.z], 1);
    } else if (b < CNT_BLKS + CW_BLKS) {
        int idx = (b - CNT_BLKS) * 256 + threadIdx.x;   // 0 .. 131071
        if (idx >= N_RELS * IN_DIM * OUT_DIM) return;
        int e  = idx & 7;
        int l  = (idx >> 3) & 63;
        int ks = (idx >> 9) & 31;
        int nt = idx >> 14;
        int o = nt * 16 + (l & 15);
        int k = ks * 32 + (l >> 4) * 8 + e;             // global K index
        Wtf[idx] = f2bf(W[(k >> 7) * (IN_DIM * OUT_DIM) + (k & 127) * OUT_DIM + o]);
    } else {
        int t = (b - CNT_BLKS - CW_BLKS) * 256 + threadIdx.x;   // 8 floats each
        if (t >= N_NODES * IN_DIM / 8) return;
        const float4* f4 = (const float4*)features;
        float4 x = f4[2 * t], y = f4[2 * t + 1];
        uint4 o;
        o.x = (unsigned)f2bf(x.x) | ((unsigned)f2bf(x.y) << 16);
        o.y = (unsigned)f2bf(x.z) | ((unsigned)f2bf(x.w) << 16);
        o.z = (unsigned)f2bf(y.x) | ((unsigned)f2bf(y.y) << 16);
        o.w = (unsigned)f2bf(y.z) | ((unsigned)f2bf(y.w) << 16);
        ((uint4*)featB)[t] = o;
    }
}

// ---------------- 2-pass scan ----------------
// R8 post-mortem: decoupled-lookback spin cost ~+37 µs vs the 3-pass trio —
// reverted. Instead, scan_mid+scan_apply fuse into one kernel: every block
// redundantly scans the 196 bsum values in LDS (784 B + ~200 insts, free) to
// derive its own prefix. No cross-block communication, one fewer dispatch.
__global__ void scan_part(const int* __restrict__ cnt, int* __restrict__ bsum) {
    __shared__ int s[256];
    int b = blockIdx.x, t = threadIdx.x;
    int base = b * SCAN_ELEMS + t * 8;
    int sum = 0;
#pragma unroll
    for (int k = 0; k < 8; ++k) {
        int i = base + k;
        sum += (i < NR) ? cnt[i] : 0;
    }
    s[t] = sum; __syncthreads();
    for (int off = 128; off > 0; off >>= 1) {
        if (t < off) s[t] += s[t + off];
        __syncthreads();
    }
    if (t == 0) bsum[b] = s[0];
}

__global__ __launch_bounds__(256) void scan_fused(
    const int* __restrict__ cnt, const int* __restrict__ bsum,
    int* __restrict__ segOff, int* __restrict__ cursor)
{
    __shared__ int s[256];
    __shared__ int sboff;
    const int b = blockIdx.x, t = threadIdx.x;

    // phase 1: scan the 196 per-block sums; this block's exclusive base
    int vb = (t < SCAN_NBLK) ? bsum[t] : 0;
    s[t] = vb; __syncthreads();
    for (int off = 1; off < 256; off <<= 1) {
        int x = (t >= off) ? s[t - off] : 0;
        __syncthreads();
        s[t] += x;
        __syncthreads();
    }
    if (t == 0) sboff = (b == 0) ? 0 : s[b - 1];
    __syncthreads();
    const int boff = sboff;

    // phase 2: per-element scan of this block's 2048 counters
    const int base = b * SCAN_ELEMS + t * 8;
    int v[8]; int sum = 0;
#pragma unroll
    for (int k = 0; k < 8; ++k) {
        int i = base + k;
        v[k] = (i < NR) ? cnt[i] : 0;
        sum += v[k];
    }
    s[t] = sum; __syncthreads();
    for (int off = 1; off < 256; off <<= 1) {
        int x = (t >= off) ? s[t - off] : 0;
        __syncthreads();
        s[t] += x;
        __syncthreads();
    }
    int run = boff + s[t] - sum;   // exclusive offset for this thread's chunk
#pragma unroll
    for (int k = 0; k < 8; ++k) {
        int i = base + k;
        if (i < NR) { segOff[i] = run; cursor[i] = run; run += v[k]; }
    }
    if (b == 0 && t == 0) segOff[NR] = N_EDGES;
}

// ---------------- scatter: 1 edge per thread (round 7 win) ----------------
__global__ void scatter_kernel(const int* __restrict__ tri, int* __restrict__ cursor,
                               int* __restrict__ sortedSrc) {
    int e = blockIdx.x * 256 + threadIdx.x;
    if (e >= N_EDGES) return;
    int src = tri[3 * e];
    int rel = tri[3 * e + 1];
    int tgt = tri[3 * e + 2];
    int p = atomicAdd(&cursor[tgt * N_RELS + rel], 1);
    sortedSrc[p] = src;
}

// ---------------- phase A: per-node segment mean -> bf16 agg row ----------------
// One wave per node; QUARTER-wave per edge: quarter q (16 lanes x 16 B) covers
// one full 256 B bf16 row, so 4 edges are in flight per wave. Pass p gives
// quarter q rel r = 4p+q. Trip count is wave-uniform jmax = max over the 4
// quarters (two full-exec shfl_xor reductions), so every __shfl executes at
// FULL exec (round-5 lesson: inactive-lane shfl reads are undefined); only the
// accumulate body is predicated by j < len. Loads/stores are dwordx4.
__global__ __launch_bounds__(256) void agg_kernel(
    const int* __restrict__ sortedSrc, const int* __restrict__ segOff,
    const unsigned short* __restrict__ featB, unsigned short* __restrict__ aggG)
{
    const int wave = threadIdx.x >> 6, lane = threadIdx.x & 63;
    const int node = blockIdx.x * 4 + wave;
    const int q = lane >> 4, l16 = lane & 15;

    int bnd = 0;
    if (lane < 9) bnd = segOff[node * N_RELS + lane];
    int s[9];
#pragma unroll
    for (int i = 0; i < 9; ++i) s[i] = __shfl(bnd, i);

    const int e0 = s[0], eN = s[8];
    int srcw = 0;
    if (e0 + lane < eN) srcw = sortedSrc[e0 + lane];   // window of 64 srcs

    const unsigned short* fb = featB + 8 * l16;        // dims 8*l16 .. 8*l16+7
    unsigned short* dst = aggG + (size_t)node * KDIM + 8 * l16;

#pragma unroll
    for (int p = 0; p < 2; ++p) {
        const int r = 4 * p + q;
        const int s0v = s[r], s1v = s[r + 1];
        const int len = s1v - s0v;
        int m0x = __shfl_xor(len, 16);                 // full exec
        int jm = (len > m0x) ? len : m0x;
        int m1x = __shfl_xor(jm, 32);                  // full exec
        const int jmax = (jm > m1x) ? jm : m1x;        // wave-uniform
        float a0 = 0.f, a1 = 0.f, a2 = 0.f, a3 = 0.f;
        float a4 = 0.f, a5 = 0.f, a6 = 0.f, a7 = 0.f;
        for (int j = 0; j < jmax; ++j) {               // uniform trip count
            const int e = s0v + j;
            const int i0 = e - e0;
            const int swin = __shfl(srcw, i0 & 63);    // full exec, safe
            if (j < len) {
                const int src = (i0 < 64) ? swin : sortedSrc[e];
                uint4 u = *(const uint4*)&fb[src * IN_DIM];
                a0 += bflo(u.x); a1 += bfhi(u.x);
                a2 += bflo(u.y); a3 += bfhi(u.y);
                a4 += bflo(u.z); a5 += bfhi(u.z);
                a6 += bflo(u.w); a7 += bfhi(u.w);
            }
        }
        const float inv = (len > 0) ? 1.0f / (float)len : 0.0f;
        uint4 pk;
        pk.x = (unsigned)f2bf(a0 * inv) | ((unsigned)f2bf(a1 * inv) << 16);
        pk.y = (unsigned)f2bf(a2 * inv) | ((unsigned)f2bf(a3 * inv) << 16);
        pk.z = (unsigned)f2bf(a4 * inv) | ((unsigned)f2bf(a5 * inv) << 16);
        pk.w = (unsigned)f2bf(a6 * inv) | ((unsigned)f2bf(a7 * inv) << 16);
        *(uint4*)&dst[r * IN_DIM] = pk;                // each quarter stores its rel row
    }
}

// ---------------- phase B: out[M_PAD x 128] = agg @ W + bias ----------------
// Block = 64 rows x 128 cols, 4 waves, wave-tile 32x64. A staged to LDS via
// global_load_lds (16 B) with XOR-16 swizzle: LDS[row][u] = global[row][u^(row&15)]
//  - staging reads: 16 contiguous lanes cover one full 256 B row segment
//  - A-frag ds_read_b128: 16 lanes hit perm(0..15) 16B units -> 2-way = free
// B-frags are contiguous 1 KB loads from fragment-major Wtf (L2-resident).
__global__ __launch_bounds__(256) void gemm_kernel(
    const unsigned short* __restrict__ aggG,
    const unsigned short* __restrict__ Wtf,
    const float* __restrict__ bias,
    float* __restrict__ out)
{
    __shared__ unsigned short Abuf[64 * 128];   // 16 KB, row stride 256 B
    const int tid = threadIdx.x;
    const int wave = tid >> 6, lane = tid & 63;
    const int qk = lane >> 4, ln16 = lane & 15;
    const int m0 = blockIdx.x * 64;
    const int wm = wave & 1, wn = wave >> 1;

    floatx4 acc[2][4];
#pragma unroll
    for (int st = 0; st < 2; ++st)
#pragma unroll
        for (int nt = 0; nt < 4; ++nt) acc[st][nt] = (floatx4){0.f, 0.f, 0.f, 0.f};

    const int l4 = lane >> 4, l15 = lane & 15;

    for (int c = 0; c < 8; ++c) {
        __syncthreads();                 // previous chunk fully consumed
#pragma unroll
        for (int i = 0; i < 4; ++i) {
            const int row = wave * 16 + i * 4 + l4;          // 0..63
            const int unit = l15 ^ (row & 15);
            const unsigned short* g =
                aggG + (size_t)(m0 + row) * KDIM + c * 128 + unit * 8;
            __builtin_amdgcn_global_load_lds(
                (const __attribute__((address_space(1))) unsigned int*)g,
                (__attribute__((address_space(3))) unsigned int*)&Abuf[(wave * 16 + i * 4) * 128],
                16, 0, 0);
        }
        __syncthreads();                 // staging visible (vmcnt drained)

#pragma unroll
        for (int ksl = 0; ksl < 4; ++ksl) {
            const int ks = c * 4 + ksl;
            bf16x8 a[2];
#pragma unroll
            for (int st = 0; st < 2; ++st) {
                const int r = wm * 32 + st * 16 + ln16;
                const int u = (ksl * 4 + qk) ^ (r & 15);
                a[st] = *(const bf16x8*)&Abuf[r * 128 + u * 8];
            }
#pragma unroll
            for (int nt = 0; nt < 4; ++nt) {
                const int ntg = wn * 4 + nt;
                bf16x8 b = *(const bf16x8*)&Wtf[(size_t)((ntg * 32 + ks) * 64 + lane) * 8];
                acc[0][nt] = __builtin_amdgcn_mfma_f32_16x16x32_bf16(a[0], b, acc[0][nt], 0, 0, 0);
                acc[1][nt] = __builtin_amdgcn_mfma_f32_16x16x32_bf16(a[1], b, acc[1][nt], 0, 0, 0);
            }
        }
    }

    // D layout: col = lane&15, row = (lane>>4)*4 + reg
#pragma unroll
    for (int nt = 0; nt < 4; ++nt) {
        const int o = (wn * 4 + nt) * 16 + ln16;
        const float bv = bias[o];
#pragma unroll
        for (int st = 0; st < 2; ++st)
#pragma unroll
            for (int j = 0; j < 4; ++j) {
                const int t = m0 + wm * 32 + st * 16 + qk * 4 + j;
                if (t < N_NODES) out[(size_t)t * OUT_DIM + o] = acc[st][nt][j] + bv;
            }
    }
}

extern "C" void kernel_launch(void* const* d_in, const int* in_sizes, int n_in,
                              void* d_out, int out_size, void* d_ws, size_t ws_size,
                              hipStream_t stream)
{
    const int*   tri      = (const int*)d_in[0];
    const float* features = (const float*)d_in[1];
    const float* W        = (const float*)d_in[2];
    const float* bias     = (const float*)d_in[3];
    float* out = (float*)d_out;

    char* ws = (char*)d_ws;
    unsigned short* Wtf = (unsigned short*)ws; ws += (size_t)OUT_DIM * KDIM * 2;  // 256 KB
    int* cnt       = (int*)ws; ws += (size_t)NR * 4;
    int* segOff    = (int*)ws; ws += (size_t)(NR + 4) * 4;
    int* cursor    = (int*)ws; ws += (size_t)NR * 4;
    int* bsum      = (int*)ws; ws += (size_t)SCAN_NBLK * 4;
    int* sortedSrc = (int*)ws; ws += (size_t)N_EDGES * 4;
    unsigned short* featB = (unsigned short*)ws; ws += (size_t)N_NODES * IN_DIM * 2;  // 12.8 MB
    unsigned short* aggG  = (unsigned short*)ws; ws += (size_t)M_PAD * KDIM * 2;      // 102.5 MB
    (void)ws_size; (void)in_sizes; (void)n_in; (void)out_size;

    hipMemsetAsync(cnt, 0, NR * sizeof(int), stream);
    prep_kernel<<<CNT_BLKS + CW_BLKS + FB_BLKS, 256, 0, stream>>>(tri, W, features, cnt, Wtf, featB);
    scan_part<<<SCAN_NBLK, 256, 0, stream>>>(cnt, bsum);
    scan_fused<<<SCAN_NBLK, 256, 0, stream>>>(cnt, bsum, segOff, cursor);
    scatter_kernel<<<(N_EDGES + 255) / 256, 256, 0, stream>>>(tri, cursor, sortedSrc);
    agg_kernel<<<N_NODES / 4, 256, 0, stream>>>(sortedSrc, segOff, featB, aggG);
    gemm_kernel<<<M_PAD / 64, 256, 0, stream>>>(aggG, Wtf, bias, out);
}